// Round 5
// baseline (359.601 us; speedup 1.0000x reference)
//
#include <hip/hip_runtime.h>
#include <hip/hip_bf16.h>

typedef __hip_bfloat16 bf16;
typedef __attribute__((ext_vector_type(8))) __bf16 bf16x8;
typedef __attribute__((ext_vector_type(4))) float f32x4;
typedef __attribute__((ext_vector_type(4))) unsigned int u32x4;

static __device__ __forceinline__ float b2f(bf16 x){ return __bfloat162float(x); }
static __device__ __forceinline__ bf16  f2b(float x){ return __float2bfloat16(x); }

constexpr int cB = 2048, cN = 64, cD = 128, cDM = 256, cH = 8, cNE = 6;
constexpr int cBN = cB * cN;                 // 131072 rows
constexpr float LNEPS = 1e-5f;
constexpr float RSQ32 = 0.17677669529663687f; // 1/sqrt(32)
constexpr int TR = 64;                        // rows per k_heavy tile
constexpr int MAXT64 = 2060;                  // >= 131072/64 + 6

// ---------------- init: zero etype counters ----------------
__global__ void k_init(int* cnt){ if (threadIdx.x < cNE) cnt[threadIdx.x] = 0; }

// ---------------- convert Wq/Wk/Wv to bf16 ----------------
__global__ __launch_bounds__(256) void k_wconv(const float* __restrict__ Wq,
        const float* __restrict__ Wk, const float* __restrict__ Wv,
        bf16* __restrict__ Wqb, bf16* __restrict__ Wkb, bf16* __restrict__ Wvb){
    int i = blockIdx.x * 256 + threadIdx.x;            // i < 98304 (x4 elems)
    const float* s = blockIdx.y == 0 ? Wq : blockIdx.y == 1 ? Wk : Wv;
    bf16* d = blockIdx.y == 0 ? Wqb : blockIdx.y == 1 ? Wkb : Wvb;
    float4 v = ((const float4*)s)[i];
    union { bf16 h[4]; uint2 u; } p;
    p.h[0] = f2b(v.x); p.h[1] = f2b(v.y); p.h[2] = f2b(v.z); p.h[3] = f2b(v.w);
    *(uint2*)&d[(size_t)i * 4] = p.u;
}

// ---------------- qcatb[b] = bf16([ln1(src[b]), src_t[b]]) ----------------
__global__ __launch_bounds__(256) void k_qprep(const float* __restrict__ src,
        const float* __restrict__ src_t, const float* __restrict__ g1,
        const float* __restrict__ b1, bf16* __restrict__ qcatb){
    int lane = threadIdx.x & 63;
    int b = blockIdx.x * 4 + (threadIdx.x >> 6);
    const float* s = src + b * cD;
    float x0 = s[lane], x1 = s[lane + 64];
    float sm = x0 + x1;
    #pragma unroll
    for (int m = 32; m; m >>= 1) sm += __shfl_xor(sm, m);
    float mu = sm * (1.0f / cD);
    float d0 = x0 - mu, d1 = x1 - mu;
    float vs = d0 * d0 + d1 * d1;
    #pragma unroll
    for (int m = 32; m; m >>= 1) vs += __shfl_xor(vs, m);
    float rs = rsqrtf(vs * (1.0f / cD) + LNEPS);
    bf16* q = qcatb + b * cDM;
    q[lane]        = f2b(d0 * rs * g1[lane] + b1[lane]);
    q[lane + 64]   = f2b(d1 * rs * g1[lane + 64] + b1[lane + 64]);
    q[cD + lane]      = f2b(src_t[b * cD + lane]);
    q[cD + lane + 64] = f2b(src_t[b * cD + lane + 64]);
}

// ------------- kvec[row] = [ln2(seq+seq_e), seq_t]; hierarchical etype scatter -------------
__global__ __launch_bounds__(256) void k_kprep(const float* __restrict__ seq,
        const float* __restrict__ seq_t, const float* __restrict__ seq_e,
        const float* __restrict__ g2, const float* __restrict__ b2v,
        const int* __restrict__ etype, bf16* __restrict__ kvec,
        int* __restrict__ cnt, int* __restrict__ eidx){
    __shared__ int lcnt[cNE];
    __shared__ int base[cNE];
    __shared__ unsigned char le[256];
    __shared__ short lp[256];
    int t = threadIdx.x;
    int l = t & 31, g = t >> 5;
    if (t < cNE) lcnt[t] = 0;
    __syncthreads();
    int row0 = blockIdx.x * 256;
    float gg[4], bb[4];
    #pragma unroll
    for (int j = 0; j < 4; ++j){ gg[j] = g2[l * 4 + j]; bb[j] = b2v[l * 4 + j]; }
    for (int pass = 0; pass < 32; ++pass){
        int lid = pass * 8 + g;
        int row = row0 + lid;
        float4 a = *(const float4*)(seq   + (size_t)row * cD + l * 4);
        float4 eV = *(const float4*)(seq_e + (size_t)row * cD + l * 4);
        float x[4] = {a.x + eV.x, a.y + eV.y, a.z + eV.z, a.w + eV.w};
        float sm = x[0] + x[1] + x[2] + x[3];
        #pragma unroll
        for (int m = 16; m; m >>= 1) sm += __shfl_xor(sm, m);
        float mu = sm * (1.0f / cD), vs = 0.f;
        #pragma unroll
        for (int j = 0; j < 4; ++j){ x[j] -= mu; vs += x[j] * x[j]; }
        #pragma unroll
        for (int m = 16; m; m >>= 1) vs += __shfl_xor(vs, m);
        float rs = rsqrtf(vs * (1.0f / cD) + LNEPS);
        bf16* kv = kvec + (size_t)row * cDM;
        union { bf16 h[4]; uint2 u; } p;
        #pragma unroll
        for (int j = 0; j < 4; ++j) p.h[j] = f2b(x[j] * rs * gg[j] + bb[j]);
        *(uint2*)&kv[l * 4] = p.u;
        float4 tv = *(const float4*)(seq_t + (size_t)row * cD + l * 4);
        p.h[0] = f2b(tv.x); p.h[1] = f2b(tv.y); p.h[2] = f2b(tv.z); p.h[3] = f2b(tv.w);
        *(uint2*)&kv[cD + l * 4] = p.u;
        if (l == 0){
            int e = etype[row];
            int pos = atomicAdd(&lcnt[e], 1);
            le[lid] = (unsigned char)e;
            lp[lid] = (short)pos;
        }
    }
    __syncthreads();
    if (t < cNE) base[t] = atomicAdd(cnt + t, lcnt[t]);
    __syncthreads();
    int e = le[t];
    eidx[e * cBN + base[e] + lp[t]] = row0 + t;
}

// ------------- Qe[b][e] = qcat[b] @ Wq[e].T via MFMA (dense, 32 b-rows/block) -------------
__global__ __launch_bounds__(256) void k_gemmQ(const bf16* __restrict__ qcatb,
        const bf16* __restrict__ Wqb, float* __restrict__ Qe){
    int t = threadIdx.x, w = t >> 6, l = t & 63;
    int lr = l & 15, lg4 = l >> 4;
    int b0 = blockIdx.x * 32, e = blockIdx.y;
    const char* A  = (const char*)qcatb + (size_t)b0 * 512;
    const char* Wq = (const char*)(Wqb + (size_t)e * 65536);
    int colbase = w * 64;
    f32x4 acc[2][4] = {};
    #pragma unroll
    for (int ks = 0; ks < 8; ++ks){
        int kb = ks * 64 + lg4 * 16;
        bf16x8 a0 = *(const bf16x8*)(A + (size_t)lr * 512 + kb);
        bf16x8 a1 = *(const bf16x8*)(A + (size_t)(16 + lr) * 512 + kb);
        #pragma unroll
        for (int cf = 0; cf < 4; ++cf){
            bf16x8 bq = *(const bf16x8*)(Wq + (size_t)(colbase + cf * 16 + lr) * 512 + kb);
            acc[0][cf] = __builtin_amdgcn_mfma_f32_16x16x32_bf16(a0, bq, acc[0][cf], 0, 0, 0);
            acc[1][cf] = __builtin_amdgcn_mfma_f32_16x16x32_bf16(a1, bq, acc[1][cf], 0, 0, 0);
        }
    }
    #pragma unroll
    for (int rf = 0; rf < 2; ++rf)
        #pragma unroll
        for (int cf = 0; cf < 4; ++cf)
            #pragma unroll
            for (int j = 0; j < 4; ++j){
                int b = b0 + rf * 16 + lg4 * 4 + j;
                Qe[((size_t)b * cNE + e) * cDM + colbase + cf * 16 + lr] = acc[rf][cf][j];
            }
}

// ------------- build tile list: (e, tile-within-e) packed, 64 rows/tile -------------
__global__ void k_tiles(const int* __restrict__ cnt, int* __restrict__ tiles,
                        int* __restrict__ ntiles){
    __shared__ int off[cNE + 1];
    if (threadIdx.x == 0){
        int s = 0;
        for (int e = 0; e < cNE; ++e){ off[e] = s; s += (cnt[e] + TR - 1) / TR; }
        off[cNE] = s;
        *ntiles = s;
    }
    __syncthreads();
    int nt = off[cNE];
    for (int i = threadIdx.x; i < nt; i += blockDim.x){
        int e = 0;
        while (off[e + 1] <= i) ++e;
        tiles[i] = (e << 16) | (i - off[e]);
    }
}

// ------------- grouped K/V projection via MFMA + attention logits (v3, TR=64) -------------
// 512 threads = 8 waves; wave w owns cols [32w,32w+32) == head w, ALL 64 rows.
// Per ks: 8 B-prefetch loads (1-deep dbuf) vs 16 MFMAs. Qe loaded in epilogue only.
__global__ __launch_bounds__(512, 2) void k_heavy(const bf16* __restrict__ kvec,
        const bf16* __restrict__ Wkb, const bf16* __restrict__ Wvb,
        const float* __restrict__ Qe, const float* __restrict__ rpri,
        const int* __restrict__ utype, const int* __restrict__ maskp,
        const int* __restrict__ cnt, const int* __restrict__ eidx,
        const int* __restrict__ tiles, const int* __restrict__ ntiles,
        float* __restrict__ logits, bf16* __restrict__ Vmat){
    __shared__ __align__(16) unsigned char Alds[TR * 512];   // 32 KB
    __shared__ int s_row[TR], s_qo[TR], s_msk[TR], s_nrr[1];
    __shared__ float s_pri[TR];
    __shared__ float s_lg[TR * 8];
    if ((int)blockIdx.x >= *ntiles) return;
    int t = threadIdx.x;
    int info = tiles[blockIdx.x];
    int e = info >> 16, r0 = (info & 0xffff) * TR;
    if (t < TR){
        int ce = cnt[e];
        int nr = min(TR, ce - r0);
        int rr = (t < nr) ? r0 + t : r0;       // clamp tail to first row of tile
        int row = eidx[e * cBN + rr];
        s_row[t] = row;
        int b = row >> 6;
        s_qo[t] = (b * cNE + e) * cDM;
        s_pri[t] = rpri[utype[b] * cNE + e];
        s_msk[t] = (t < nr) ? maskp[row] : -1; // -1 => invalid row, skip stores
        if (t == 0) s_nrr[0] = nr;
    }
    __syncthreads();
    int w = t >> 6, l = t & 63;
    int lr = l & 15, lg4 = l >> 4;
    int colbase = w * 32;
    // stage A: 64 rows x 512B, 16B chunks, write-side XOR swizzle
    #pragma unroll
    for (int i = 0; i < 4; ++i){
        int idx = t + i * 512, r = idx >> 5, ck = (idx & 31) * 16;
        u32x4 dv = *(const u32x4*)((const char*)kvec + (size_t)s_row[r] * 512 + ck);
        *(u32x4*)(Alds + r * 512 + (ck ^ ((r & 7) << 4))) = dv;
    }
    __syncthreads();                           // A visible in LDS
    const char* WK = (const char*)(Wkb + (size_t)e * 65536);
    const char* WV = (const char*)(Wvb + (size_t)e * 65536);
    f32x4 aK[4][2] = {}, aV[4][2] = {};
    bf16x8 bk[2][2], bv[2][2];                 // [buf][cf]
    int bcol0 = (colbase + lr) * 512;
    int bcol1 = (colbase + 16 + lr) * 512;
    int kb0 = lg4 * 16;
    bk[0][0] = *(const bf16x8*)(WK + bcol0 + kb0);
    bk[0][1] = *(const bf16x8*)(WK + bcol1 + kb0);
    bv[0][0] = *(const bf16x8*)(WV + bcol0 + kb0);
    bv[0][1] = *(const bf16x8*)(WV + bcol1 + kb0);
    int axor = (lr & 7) << 4;
    #pragma unroll
    for (int ks = 0; ks < 8; ++ks){
        int cur = ks & 1, nxt = cur ^ 1;
        if (ks < 7){
            int kb = (ks + 1) * 64 + lg4 * 16;
            bk[nxt][0] = *(const bf16x8*)(WK + bcol0 + kb);
            bk[nxt][1] = *(const bf16x8*)(WK + bcol1 + kb);
            bv[nxt][0] = *(const bf16x8*)(WV + bcol0 + kb);
            bv[nxt][1] = *(const bf16x8*)(WV + bcol1 + kb);
        }
        int kb = ks * 64 + lg4 * 16;
        #pragma unroll
        for (int rf = 0; rf < 4; ++rf){
            bf16x8 af = *(const bf16x8*)(Alds + (lr + rf * 16) * 512 + (kb ^ axor));
            aK[rf][0] = __builtin_amdgcn_mfma_f32_16x16x32_bf16(af, bk[cur][0], aK[rf][0], 0, 0, 0);
            aK[rf][1] = __builtin_amdgcn_mfma_f32_16x16x32_bf16(af, bk[cur][1], aK[rf][1], 0, 0, 0);
            aV[rf][0] = __builtin_amdgcn_mfma_f32_16x16x32_bf16(af, bv[cur][0], aV[rf][0], 0, 0, 0);
            aV[rf][1] = __builtin_amdgcn_mfma_f32_16x16x32_bf16(af, bv[cur][1], aV[rf][1], 0, 0, 0);
        }
    }
    // ---- epilogue 1: logits. Qe gathered NOW (not live during loop). ----
    #pragma unroll
    for (int rf = 0; rf < 4; ++rf)
        #pragma unroll
        for (int j = 0; j < 4; ++j){
            int row = rf * 16 + lg4 * 4 + j;
            const float* qp = Qe + s_qo[row] + colbase + lr;
            float p = aK[rf][0][j] * qp[0] + aK[rf][1][j] * qp[16];
            p += __shfl_xor(p, 1); p += __shfl_xor(p, 2);
            p += __shfl_xor(p, 4); p += __shfl_xor(p, 8);
            if (lr == 0) s_lg[row * 8 + w] = p;
        }
    __syncthreads();                           // s_lg ready; all A-reads retired
    {
        int row = t >> 3, h = t & 7;           // 64 rows x 8 heads == 512 threads
        if (s_msk[row] >= 0){
            int grow = s_row[row];
            float lgv = s_msk[row] ? -1e10f : s_lg[row * 8 + h] * s_pri[row] * RSQ32;
            logits[((size_t)h * cB + (grow >> 6)) * cN + (grow & 63)] = lgv;
        }
    }
    // ---- epilogue 2: V repack via LDS (swizzled), coalesced 16B stores ----
    #pragma unroll
    for (int rf = 0; rf < 4; ++rf)
        #pragma unroll
        for (int cf = 0; cf < 2; ++cf)
            #pragma unroll
            for (int j = 0; j < 4; ++j){
                int row = rf * 16 + lg4 * 4 + j;
                int byt = (colbase + cf * 16 + lr) * 2;
                *(bf16*)(Alds + row * 512 + (byt ^ ((row & 7) << 4))) = f2b(aV[rf][cf][j]);
            }
    __syncthreads();
    int nr = s_nrr[0];
    #pragma unroll
    for (int i = 0; i < 4; ++i){
        int idx = t + i * 512, r = idx >> 5, ck = (idx & 31) * 16;
        if (r < nr)
            *(u32x4*)((char*)Vmat + (size_t)s_row[r] * 512 + ck) =
                *(const u32x4*)(Alds + r * 512 + (ck ^ ((r & 7) << 4)));
    }
}

// ------------- softmax, attn out, V-weighted sum, fc, ln3, mlp -------------
__global__ __launch_bounds__(256) void k_final(const float* __restrict__ logits,
        const bf16* __restrict__ Vmat, const float* __restrict__ src,
        const float* __restrict__ fc_w, const float* __restrict__ fc_b,
        const float* __restrict__ g3, const float* __restrict__ b3,
        const float* __restrict__ m1w, const float* __restrict__ m1b,
        const float* __restrict__ m2w, const float* __restrict__ m2b,
        const int* __restrict__ utype,
        float* __restrict__ outF, float* __restrict__ outA){
    __shared__ float p[cH][cN];
    __shared__ __align__(16) float ov[cDM];
    __shared__ __align__(16) float cat[cDM + cD];
    __shared__ __align__(16) float hm[cD];
    __shared__ float red[8];
    int b = blockIdx.x, t = threadIdx.x;
    int h = t >> 5, i = t & 31;
    const float* lgp = logits + ((size_t)h * cB + b) * cN;
    float l0 = lgp[i], l1 = lgp[i + 32];
    float mx = fmaxf(l0, l1);
    #pragma unroll
    for (int m = 16; m; m >>= 1) mx = fmaxf(mx, __shfl_xor(mx, m));
    float e0 = expf(l0 - mx), e1 = expf(l1 - mx);
    float sm = e0 + e1;
    #pragma unroll
    for (int m = 16; m; m >>= 1) sm += __shfl_xor(sm, m);
    float inv = 1.0f / sm;
    e0 *= inv; e1 *= inv;
    p[h][i] = e0; p[h][i + 32] = e1;
    float* ap = outA + ((size_t)h * cB + b) * cN;
    ap[i] = e0; ap[i + 32] = e1;
    __syncthreads();
    // attn-weighted V: col t belongs to head t>>5
    float acc = 0.f;
    const bf16* vb = Vmat + (size_t)b * cN * cDM + t;
    #pragma unroll 4
    for (int n = 0; n < cN; ++n) acc = fmaf(p[t >> 5][n], b2f(vb[(size_t)n * cDM]), acc);
    ov[t] = acc;
    __syncthreads();
    // fc by utype (float4 weight loads)
    int u = utype[b];
    const float4* fw4 = (const float4*)(fc_w + ((size_t)u * cDM + t) * cDM);
    float a2 = fc_b[u * cDM + t];
    #pragma unroll 8
    for (int k = 0; k < cDM / 4; ++k){
        float4 wv = fw4[k];
        float4 o = *(const float4*)&ov[k * 4];
        a2 = fmaf(wv.x, o.x, fmaf(wv.y, o.y, fmaf(wv.z, o.z, fmaf(wv.w, o.w, a2))));
    }
    // ln3 (block reduce over 256)
    float s1 = a2, s2 = a2 * a2;
    #pragma unroll
    for (int m = 32; m; m >>= 1){ s1 += __shfl_xor(s1, m); s2 += __shfl_xor(s2, m); }
    if ((t & 63) == 0){ red[t >> 6] = s1; red[4 + (t >> 6)] = s2; }
    __syncthreads();
    s1 = red[0] + red[1] + red[2] + red[3];
    s2 = red[4] + red[5] + red[6] + red[7];
    float mu = s1 * (1.0f / cDM);
    float var = s2 * (1.0f / cDM) - mu * mu;
    float rs = rsqrtf(var + LNEPS);
    cat[t] = (a2 - mu) * rs * g3[t] + b3[t];
    if (t < cD) cat[cDM + t] = src[b * cD + t];
    __syncthreads();
    if (t < cD){
        const float4* w14 = (const float4*)(m1w + (size_t)t * (cDM + cD));
        float a = m1b[t];
        #pragma unroll 8
        for (int k = 0; k < (cDM + cD) / 4; ++k){
            float4 wv = w14[k];
            float4 o = *(const float4*)&cat[k * 4];
            a = fmaf(wv.x, o.x, fmaf(wv.y, o.y, fmaf(wv.z, o.z, fmaf(wv.w, o.w, a))));
        }
        hm[t] = fmaxf(a, 0.f);
    }
    __syncthreads();
    if (t < cD){
        const float4* w24 = (const float4*)(m2w + (size_t)t * cD);
        float a = m2b[t];
        #pragma unroll 8
        for (int k = 0; k < cD / 4; ++k){
            float4 wv = w24[k];
            float4 o = *(const float4*)&hm[k * 4];
            a = fmaf(wv.x, o.x, fmaf(wv.y, o.y, fmaf(wv.z, o.z, fmaf(wv.w, o.w, a))));
        }
        outF[(size_t)b * cD + t] = a;
    }
}

extern "C" void kernel_launch(void* const* d_in, const int* in_sizes, int n_in,
                              void* d_out, int out_size, void* d_ws, size_t ws_size,
                              hipStream_t stream) {
    const float* src    = (const float*)d_in[0];
    const float* src_t  = (const float*)d_in[1];
    const float* seq    = (const float*)d_in[2];
    const float* seq_t  = (const float*)d_in[3];
    const float* seq_e  = (const float*)d_in[4];
    const float* Wq     = (const float*)d_in[5];
    const float* Wk     = (const float*)d_in[6];
    const float* Wv     = (const float*)d_in[7];
    const float* rpri   = (const float*)d_in[8];
    const float* fc_w   = (const float*)d_in[9];
    const float* fc_b   = (const float*)d_in[10];
    const float* ln1g   = (const float*)d_in[11];
    const float* ln1b   = (const float*)d_in[12];
    const float* ln2g   = (const float*)d_in[13];
    const float* ln2b   = (const float*)d_in[14];
    const float* ln3g   = (const float*)d_in[15];
    const float* ln3b   = (const float*)d_in[16];
    const float* m1w    = (const float*)d_in[17];
    const float* m1b    = (const float*)d_in[18];
    const float* m2w    = (const float*)d_in[19];
    const float* m2b    = (const float*)d_in[20];
    const int*  etype   = (const int*)d_in[21];
    const int*  utype   = (const int*)d_in[22];
    const int*  maskp   = (const int*)d_in[24];

    // workspace layout (f32 regions first, then bf16, then int)
    float* Qe     = (float*)d_ws;                          // B*NE*DM
    float* logits = Qe + (size_t)cB * cNE * cDM;           // H*B*N
    bf16*  qcatb  = (bf16*)(logits + (size_t)cH * cB * cN);// B*DM
    bf16*  kvec   = qcatb + (size_t)cB * cDM;              // BN*DM
    bf16*  Vmat   = kvec + (size_t)cBN * cDM;              // BN*DM
    bf16*  Wqb    = Vmat + (size_t)cBN * cDM;              // NE*DM*DM
    bf16*  Wkb    = Wqb + (size_t)cNE * cDM * cDM;
    bf16*  Wvb    = Wkb + (size_t)cNE * cDM * cDM;
    int*   cnt    = (int*)(Wvb + (size_t)cNE * cDM * cDM); // 8
    int*   eidx   = cnt + 8;                               // NE*BN
    int*   tiles  = eidx + (size_t)cNE * cBN;              // MAXT64
    int*   ntiles = tiles + MAXT64;                        // 1

    float* outF = (float*)d_out;
    float* outA = outF + (size_t)cB * cD;

    k_init<<<dim3(1), dim3(64), 0, stream>>>(cnt);
    k_wconv<<<dim3(384, 3), dim3(256), 0, stream>>>(Wq, Wk, Wv, Wqb, Wkb, Wvb);
    k_qprep<<<dim3(cB / 4), dim3(256), 0, stream>>>(src, src_t, ln1g, ln1b, qcatb);
    k_kprep<<<dim3(cBN / 256), dim3(256), 0, stream>>>(seq, seq_t, seq_e, ln2g, ln2b,
                                                       etype, kvec, cnt, eidx);
    k_gemmQ<<<dim3(cB / 32, cNE), dim3(256), 0, stream>>>(qcatb, Wqb, Qe);
    k_tiles<<<dim3(1), dim3(256), 0, stream>>>(cnt, tiles, ntiles);
    k_heavy<<<dim3(MAXT64), dim3(512), 0, stream>>>(kvec, Wkb, Wvb, Qe, rpri, utype,
                                                    maskp, cnt, eidx, tiles, ntiles,
                                                    logits, Vmat);
    k_final<<<dim3(cB), dim3(256), 0, stream>>>(logits, Vmat, src, fc_w, fc_b,
                                                ln3g, ln3b, m1w, m1b, m2w, m2b,
                                                utype, outF, outA);
}